// Round 6
// baseline (539.603 us; speedup 1.0000x reference)
//
#include <hip/hip_runtime.h>
#include <hip/hip_bf16.h>
#include <stdint.h>

typedef __attribute__((ext_vector_type(8))) short short8;
typedef __attribute__((ext_vector_type(4))) float floatx4;
typedef _Float16 half8 __attribute__((ext_vector_type(8)));

#define AS1 __attribute__((address_space(1)))
#define AS3 __attribute__((address_space(3)))

__device__ __forceinline__ void gload_lds16(const void* g, void* l) {
    __builtin_amdgcn_global_load_lds((const AS1 void*)g, (AS3 void*)l, 16, 0, 0);
}

// ---------------------------------------------------------------------------
// fp32-accurate GEMM via fp16 2-way split + 3-product MFMA:
//   C[M,N] = A[M,K](fp32) @ Bt[N,K]^T (+bias)  =  Ah*Bh + Al*Bh + Ah*Bl,
//   a = ah + al (f16 hi/lo, 11+11 mantissa bits) -> fp32-class argmin safety.
//
// Pipelined (T3-minimum): BK=32, double-buffered LDS, ONE barrier per K-tile;
// next tile's B global_load_lds and A fp32 reg-loads are issued BEFORE the
// current tile's compute, so their latency hides under 48 MFMA + the sibling
// block (2 blocks/CU at 64 KB LDS). A is split (cvt) after compute, written
// to the other buffer; barrier drains everything once.
//
// LDS layout (per operand, per buffer): [128 rows][8 slots of 16B].
// Data chunk d = slot ^ (r&7);  d<4 : hi f16 of k-oct d;  d>=4 : lo of d-4.
// Same proven conflict-free XOR addressing as the bf16 gemm_bt kernel.
// Bt must have ceil(N/128)*128 rows (zero-padded). Col-guarded store.
// ---------------------------------------------------------------------------
__global__ __launch_bounds__(256, 2) void mgemm(
    const float* __restrict__ A, const _Float16* __restrict__ BtHi,
    const _Float16* __restrict__ BtLo, const float* __restrict__ bias,
    float* __restrict__ C, int M, int N, int K) {
    __shared__ _Float16 sA[2][128 * 64];   // 16 KB x2
    __shared__ _Float16 sB[2][128 * 64];   // 16 KB x2
    const int t = threadIdx.x;
    const int lane = t & 63, w = t >> 6;
    const int wr = w >> 1, wc = w & 1;
    const int m16 = lane & 15, q = lane >> 4;
    const long row0 = (long)blockIdx.y * 128;
    const long col0 = (long)blockIdx.x * 128;

    // A staging: thread handles row rT, k-half h (16 floats = octs h*2,h*2+1)
    const int rT = t >> 1;
    const int h = t & 1;
    const int rk7 = rT & 7;

    floatx4 acc[4][4];
#pragma unroll
    for (int i = 0; i < 4; i++)
#pragma unroll
        for (int j = 0; j < 4; j++) acc[i][j] = (floatx4){0.f, 0.f, 0.f, 0.f};

    floatx4 av0, av1, av2, av3;   // A prefetch (16 VGPR, live across compute)

#define ALOAD(kk)                                                             \
    do {                                                                      \
        const float* ap = A + (row0 + rT) * (long)K + (kk) + h * 16;          \
        av0 = *(const floatx4*)ap;                                            \
        av1 = *(const floatx4*)(ap + 4);                                      \
        av2 = *(const floatx4*)(ap + 8);                                      \
        av3 = *(const floatx4*)(ap + 12);                                     \
    } while (0)

#define BSTAGE(buf, kk)                                                       \
    do {                                                                      \
        _Pragma("unroll")                                                     \
        for (int i = 0; i < 4; i++) {                                         \
            const int li = i * 256 + t;                                       \
            const int r = li >> 3, s = li & 7;                                \
            const int d = s ^ (r & 7);                                        \
            const _Float16* src = (d < 4)                                     \
                ? BtHi + (col0 + r) * (long)K + (kk) + d * 8                  \
                : BtLo + (col0 + r) * (long)K + (kk) + (d - 4) * 8;           \
            gload_lds16(src, (char*)&sB[buf][0] + (size_t)li * 16);           \
        }                                                                     \
    } while (0)

#define AWRITE(buf)                                                           \
    do {                                                                      \
        half8 hA, hB, lA, lB;                                                 \
        _Pragma("unroll")                                                     \
        for (int j = 0; j < 4; j++) {                                         \
            _Float16 x0 = (_Float16)av0[j];                                   \
            hA[j] = x0; lA[j] = (_Float16)(av0[j] - (float)x0);               \
            _Float16 x1 = (_Float16)av1[j];                                   \
            hA[4 + j] = x1; lA[4 + j] = (_Float16)(av1[j] - (float)x1);       \
            _Float16 x2 = (_Float16)av2[j];                                   \
            hB[j] = x2; lB[j] = (_Float16)(av2[j] - (float)x2);               \
            _Float16 x3 = (_Float16)av3[j];                                   \
            hB[4 + j] = x3; lB[4 + j] = (_Float16)(av3[j] - (float)x3);       \
        }                                                                     \
        char* base = (char*)&sA[buf][0] + (size_t)rT * 128;                   \
        *(half8*)(base + (((h * 2)     ^ rk7) << 4)) = hA;                    \
        *(half8*)(base + (((h * 2 + 1) ^ rk7) << 4)) = hB;                    \
        *(half8*)(base + (((4 + h * 2) ^ rk7) << 4)) = lA;                    \
        *(half8*)(base + (((5 + h * 2) ^ rk7) << 4)) = lB;                    \
    } while (0)

    ALOAD(0);
    BSTAGE(0, 0);
    AWRITE(0);
    __syncthreads();

    const int T = K >> 5;   // BK = 32
    for (int tt = 0; tt < T; tt++) {
        const int cur = tt & 1;
        const bool more = (tt + 1) < T;
        if (more) {
            const int kk = (tt + 1) << 5;
            ALOAD(kk);            // fp32 A -> regs (oldest vmem, waits cheap)
            BSTAGE(cur ^ 1, kk);  // pre-split B -> other LDS buffer (async)
        }
        // compute current tile: 16 ds_read_b128 + 48 MFMA per wave
        {
            const _Float16* a = &sA[cur][0];
            const _Float16* b = &sB[cur][0];
            half8 ah[4], al[4], bh[4], bl[4];
#pragma unroll
            for (int i = 0; i < 4; i++) {
                const int ra = wr * 64 + i * 16 + m16;
                const size_t ba = (size_t)ra * 128;
                ah[i] = *(const half8*)((const char*)a + ba + (((q)     ^ (ra & 7)) << 4));
                al[i] = *(const half8*)((const char*)a + ba + (((4 + q) ^ (ra & 7)) << 4));
                const int rb = wc * 64 + i * 16 + m16;
                const size_t bb = (size_t)rb * 128;
                bh[i] = *(const half8*)((const char*)b + bb + (((q)     ^ (rb & 7)) << 4));
                bl[i] = *(const half8*)((const char*)b + bb + (((4 + q) ^ (rb & 7)) << 4));
            }
#pragma unroll
            for (int i = 0; i < 4; i++)
#pragma unroll
                for (int j = 0; j < 4; j++) {
                    acc[i][j] = __builtin_amdgcn_mfma_f32_16x16x32_f16(ah[i], bh[j], acc[i][j], 0, 0, 0);
                    acc[i][j] = __builtin_amdgcn_mfma_f32_16x16x32_f16(al[i], bh[j], acc[i][j], 0, 0, 0);
                    acc[i][j] = __builtin_amdgcn_mfma_f32_16x16x32_f16(ah[i], bl[j], acc[i][j], 0, 0, 0);
                }
        }
        if (more) AWRITE(cur ^ 1);  // split+write A into other buffer
        __syncthreads();            // drains B gloads + A ds_writes once
    }
#undef ALOAD
#undef BSTAGE
#undef AWRITE

#pragma unroll
    for (int i = 0; i < 4; i++) {
#pragma unroll
        for (int j = 0; j < 4; j++) {
#pragma unroll
            for (int r4 = 0; r4 < 4; r4++) {
                long gr = row0 + wr * 64 + i * 16 + q * 4 + r4;
                int gc = (int)col0 + wc * 64 + j * 16 + m16;
                if (gc < N)
                    C[gr * (long)N + gc] = acc[i][j][r4] + (bias ? bias[gc] : 0.f);
            }
        }
    }
}

// ---------------------------------------------------------------------------
// bf16 MFMA GEMM for the output projection (precision non-critical):
// C_f32[M,N] = A_bf16[M,K] @ Bt_bf16[N,K]^T + bias_f32. 128x128 tile, BK=64.
// ---------------------------------------------------------------------------
__global__ __launch_bounds__(256) void gemm_bt(
    const __hip_bfloat16* __restrict__ A, const __hip_bfloat16* __restrict__ Bt,
    const float* __restrict__ bias, float* __restrict__ C,
    int M, int N, int K) {
    __shared__ __hip_bfloat16 sA[128 * 64];
    __shared__ __hip_bfloat16 sB[128 * 64];
    const int t = threadIdx.x;
    const int lane = t & 63, w = t >> 6;
    const int wr = w >> 1, wc = w & 1;
    const int m16 = lane & 15, q = lane >> 4;
    const long row0 = (long)blockIdx.x * 128;
    const long col0 = (long)blockIdx.y * 128;
    const int wbase = w * 64;

    floatx4 acc[4][4];
#pragma unroll
    for (int i = 0; i < 4; i++)
#pragma unroll
        for (int j = 0; j < 4; j++) acc[i][j] = (floatx4){0.f, 0.f, 0.f, 0.f};

    for (int kk = 0; kk < K; kk += 64) {
        __syncthreads();
#pragma unroll
        for (int i = 0; i < 4; i++) {
            int li = i * 256 + t;
            int r = li >> 3, c = li & 7;
            int sc = (c ^ (r & 7)) << 3;
            gload_lds16(A + (row0 + r) * (long)K + kk + sc,
                        (char*)sA + (size_t)(i * 256 + wbase) * 16);
            gload_lds16(Bt + (col0 + r) * (long)K + kk + sc,
                        (char*)sB + (size_t)(i * 256 + wbase) * 16);
        }
        __syncthreads();
#pragma unroll
        for (int s = 0; s < 2; s++) {
            short8 af[4], bf[4];
#pragma unroll
            for (int i = 0; i < 4; i++) {
                int ra = wr * 64 + i * 16 + m16;
                int cq = s * 4 + q;
                af[i] = *(const short8*)((const char*)sA + (size_t)(ra * 8 + (cq ^ (ra & 7))) * 16);
                int rb = wc * 64 + i * 16 + m16;
                bf[i] = *(const short8*)((const char*)sB + (size_t)(rb * 8 + (cq ^ (rb & 7))) * 16);
            }
#pragma unroll
            for (int i = 0; i < 4; i++)
#pragma unroll
                for (int j = 0; j < 4; j++)
                    acc[i][j] = __builtin_amdgcn_mfma_f32_16x16x32_bf16(af[i], bf[j], acc[i][j], 0, 0, 0);
        }
    }
#pragma unroll
    for (int i = 0; i < 4; i++) {
#pragma unroll
        for (int j = 0; j < 4; j++) {
#pragma unroll
            for (int r = 0; r < 4; r++) {
                long gr = row0 + wr * 64 + i * 16 + q * 4 + r;
                long gc = col0 + wc * 64 + j * 16 + m16;
                C[gr * N + gc] = acc[i][j][r] + bias[gc];
            }
        }
    }
}

// ---------------------------------------------------------------------------
// setup kernels
// ---------------------------------------------------------------------------
// Codebook split: cb_hi/lo[512][256] f16 (rows 448..511 zero) + esq[448].
__global__ __launch_bounds__(256) void setup_cb(
    const float* __restrict__ e0, const float* __restrict__ e1,
    const float* __restrict__ e2, _Float16* __restrict__ cbHi,
    _Float16* __restrict__ cbLo, float* __restrict__ esq) {
    int n = blockIdx.x;  // 0..511
    int p = threadIdx.x; // 0..255
    float v = 0.f;
    if (n < 64)       v = e0[n * 256 + p];
    else if (n < 192) v = e1[(n - 64) * 256 + p];
    else if (n < 448) v = e2[(n - 192) * 256 + p];
    _Float16 h = (_Float16)v;
    cbHi[n * 256 + p] = h;
    cbLo[n * 256 + p] = (_Float16)(v - (float)h);
    if (n < 448) {
        float s = v * v;
        for (int off = 32; off; off >>= 1) s += __shfl_xor(s, off);
        __shared__ float ps[4];
        if ((p & 63) == 0) ps[p >> 6] = s;
        __syncthreads();
        if (p == 0) esq[n] = ps[0] + ps[1] + ps[2] + ps[3];
    }
}

// W_in [1408][256] -> WinT_hi/lo [256][1408] f16. LDS tile transpose,
// coalesced both sides. grid (22, 4): 64x64 tiles.
__global__ __launch_bounds__(256) void split_win(
    const float* __restrict__ W_in, _Float16* __restrict__ wHi,
    _Float16* __restrict__ wLo) {
    __shared__ float tile[64][65];
    const int t = threadIdx.x;
    const int d0 = blockIdx.x * 64, p0 = blockIdx.y * 64;
#pragma unroll
    for (int i = 0; i < 16; i++) {
        int li = i * 256 + t;
        int dr = li >> 6, pc = li & 63;
        tile[dr][pc] = W_in[(long)(d0 + dr) * 256 + p0 + pc];
    }
    __syncthreads();
#pragma unroll
    for (int i = 0; i < 16; i++) {
        int li = i * 256 + t;
        int pr = li >> 6, dc = li & 63;
        float v = tile[dc][pr];
        _Float16 hv = (_Float16)v;
        wHi[(long)(p0 + pr) * 1408 + d0 + dc] = hv;
        wLo[(long)(p0 + pr) * 1408 + d0 + dc] = (_Float16)(v - (float)hv);
    }
}

// W_out [256][1408] -> WoutT [1408][256] bf16. LDS tile transpose. grid (22,4).
__global__ __launch_bounds__(256) void wout_transpose(
    const float* __restrict__ W_out, __hip_bfloat16* __restrict__ WoutT) {
    __shared__ float tile[64][65];
    const int t = threadIdx.x;
    const int d0 = blockIdx.x * 64, p0 = blockIdx.y * 64;
#pragma unroll
    for (int i = 0; i < 16; i++) {
        int li = i * 256 + t;
        int pr = li >> 6, dc = li & 63;
        tile[pr][dc] = W_out[(long)(p0 + pr) * 1408 + d0 + dc];
    }
    __syncthreads();
#pragma unroll
    for (int i = 0; i < 16; i++) {
        int li = i * 256 + t;
        int dr = li >> 6, pc = li & 63;
        WoutT[(long)(d0 + dr) * 256 + p0 + pc] = __float2bfloat16(tile[pc][dr]);
    }
}

__global__ __launch_bounds__(256) void gram_kernel(
    const float* __restrict__ e0, const float* __restrict__ e1,
    const float* __restrict__ e2, float* __restrict__ G01,
    float* __restrict__ G02, float* __restrict__ G12) {
    int id = blockIdx.x * 256 + threadIdx.x;  // 57344 total
    const float *a, *b;
    float* dst;
    if (id < 8192)       { a = e0 + (id >> 7) * 256;  b = e1 + (id & 127) * 256;  dst = G01 + id; }
    else if (id < 24576) { int p = id - 8192;  a = e0 + (p >> 8) * 256; b = e2 + (p & 255) * 256; dst = G02 + p; }
    else                 { int p = id - 24576; a = e1 + (p >> 8) * 256; b = e2 + (p & 255) * 256; dst = G12 + p; }
    float s = 0.f;
    for (int j = 0; j < 256; j += 4) {
        floatx4 av = *(const floatx4*)(a + j);
        floatx4 bv = *(const floatx4*)(b + j);
        s += av[0] * bv[0] + av[1] * bv[1] + av[2] * bv[2] + av[3] * bv[3];
    }
    *dst = s;
}

// ---------------------------------------------------------------------------
// VQ: one wave per row; xor-shuffle argmin with first-index tie-break.
// Gram trick: r_l . e_k = S[k] - sum of gram corrections; ||r_l||^2 = d_{l-1}.
// ---------------------------------------------------------------------------
__device__ __forceinline__ void argmin_reduce(float& d, int& k) {
#pragma unroll
    for (int off = 32; off; off >>= 1) {
        float od = __shfl_xor(d, off);
        int ok = __shfl_xor(k, off);
        if (od < d || (od == d && ok < k)) { d = od; k = ok; }
    }
}

__global__ __launch_bounds__(256) void vq_kernel(
    const float* __restrict__ Zp, const float* __restrict__ S,
    const float* __restrict__ esq, const float* __restrict__ G01,
    const float* __restrict__ G02, const float* __restrict__ G12,
    const float* __restrict__ e0, const float* __restrict__ e1,
    const float* __restrict__ e2, __hip_bfloat16* __restrict__ zq,
    float* __restrict__ out_idx, float* __restrict__ part) {
    const int t = threadIdx.x;
    const int lane = t & 63, w = t >> 6;
    const long row = (long)blockIdx.x * 4 + w;
    const float* Srow = S + row * 448;

    floatx4 zv = *(const floatx4*)(Zp + row * 256 + lane * 4);
    float rsq = zv[0] * zv[0] + zv[1] * zv[1] + zv[2] * zv[2] + zv[3] * zv[3];
    for (int off = 32; off; off >>= 1) rsq += __shfl_xor(rsq, off);

    // level 0 (K=64)
    float d = rsq - 2.0f * Srow[lane] + esq[lane];
    int bi = lane;
    argmin_reduce(d, bi);
    const float d0 = d; const int i0 = bi;

    // level 1 (K=128)
    {
        float da = d0 - 2.0f * (Srow[64 + lane] - G01[i0 * 128 + lane]) + esq[64 + lane];
        float db = d0 - 2.0f * (Srow[128 + lane] - G01[i0 * 128 + 64 + lane]) + esq[128 + lane];
        d = da; bi = lane;
        if (db < da) { d = db; bi = lane + 64; }
        argmin_reduce(d, bi);
    }
    const float d1 = d; const int i1 = bi;

    // level 2 (K=256)
    {
        d = 1e30f; bi = 0;
#pragma unroll
        for (int jj = 0; jj < 4; jj++) {
            int k = jj * 64 + lane;
            float dd = d1 - 2.0f * (Srow[192 + k] - G02[i0 * 256 + k] - G12[i1 * 256 + k]) + esq[192 + k];
            if (dd < d) { d = dd; bi = k; }
        }
        argmin_reduce(d, bi);
    }
    const float d2 = d; const int i2 = bi;

    if (lane == 0) part[row] = d0 + d1 + d2;

    floatx4 a0 = *(const floatx4*)(e0 + i0 * 256 + lane * 4);
    floatx4 a1 = *(const floatx4*)(e1 + i1 * 256 + lane * 4);
    floatx4 a2 = *(const floatx4*)(e2 + i2 * 256 + lane * 4);
    short sv[4];
#pragma unroll
    for (int i = 0; i < 4; i++) {
        union { __hip_bfloat16 h; short s; } x;
        x.h = __float2bfloat16(a0[i] + a1[i] + a2[i]);
        sv[i] = x.s;
    }
    typedef __attribute__((ext_vector_type(4))) short short4v;
    short4v ov = {sv[0], sv[1], sv[2], sv[3]};
    *(short4v*)(zq + row * 256 + lane * 4) = ov;

    if (lane == 0) {
        out_idx[row] = (float)i0;
        out_idx[32768 + row] = (float)i1;
        out_idx[65536 + row] = (float)i2;
    }
}

__global__ __launch_bounds__(256) void finalize_loss(
    const float* __restrict__ part, float* __restrict__ out_loss) {
    int t = threadIdx.x;
    float s = 0.f;
    for (int i = t; i < 32768; i += 256) s += part[i];
    for (int off = 32; off; off >>= 1) s += __shfl_xor(s, off);
    __shared__ float ps[4];
    if ((t & 63) == 0) ps[t >> 6] = s;
    __syncthreads();
    if (t == 0)
        out_loss[0] = (ps[0] + ps[1] + ps[2] + ps[3]) * (0.25f / (8388608.0f * 3.0f));
}

// ---------------------------------------------------------------------------
extern "C" void kernel_launch(void* const* d_in, const int* in_sizes, int n_in,
                              void* d_out, int out_size, void* d_ws, size_t ws_size,
                              hipStream_t stream) {
    const float* z     = (const float*)d_in[0];
    const float* W_in  = (const float*)d_in[1];
    const float* b_in  = (const float*)d_in[2];
    const float* W_out = (const float*)d_in[3];
    const float* b_out = (const float*)d_in[4];
    const float* e0    = (const float*)d_in[5];
    const float* e1    = (const float*)d_in[6];
    const float* e2    = (const float*)d_in[7];
    float* out = (float*)d_out;

    char* ws = (char*)d_ws;
    float*          Zp    = (float*)ws;                        // 33,554,432 B
    float*          S     = (float*)(ws + 33554432);           // 58,720,256 B
    __hip_bfloat16* Zq    = (__hip_bfloat16*)(ws + 92274688);  // 16,777,216 B
    // Split arrays live INSIDE the Zq region: they are only needed by the
    // two mgemm calls, which complete before vq_kernel writes Zq.
    _Float16*       WinTh = (_Float16*)(ws + 92274688);        //    720,896 B
    _Float16*       WinTl = (_Float16*)(ws + 92995584);        //    720,896 B
    _Float16*       cbHi  = (_Float16*)(ws + 93716480);        //    262,144 B
    _Float16*       cbLo  = (_Float16*)(ws + 93978624);        //    262,144 B
    __hip_bfloat16* WoutT = (__hip_bfloat16*)(ws + 109051904); //    720,896 B
    float*          esq   = (float*)(ws + 110231552);          //      1,792 B
    float*          G01   = (float*)(ws + 110233344);          //     32,768 B
    float*          G02   = (float*)(ws + 110266112);          //     65,536 B
    float*          G12   = (float*)(ws + 110331648);          //    131,072 B
    float*          part  = (float*)(ws + 110462720);          //    131,072 B

    setup_cb<<<512, 256, 0, stream>>>(e0, e1, e2, cbHi, cbLo, esq);
    split_win<<<dim3(22, 4), 256, 0, stream>>>(W_in, WinTh, WinTl);
    gram_kernel<<<224, 256, 0, stream>>>(e0, e1, e2, G01, G02, G12);
    wout_transpose<<<dim3(22, 4), 256, 0, stream>>>(W_out, WoutT);

    // z_proj = z @ W_in + b_in  (f16-split 3-product MFMA, fp32-class accuracy)
    mgemm<<<dim3(2, 256), 256, 0, stream>>>(z, WinTh, WinTl, b_in, Zp,
                                            32768, 256, 1408);
    // S = z_proj @ codebooks^T  (same kernel; last col-tile guarded, cb padded)
    mgemm<<<dim3(4, 256), 256, 0, stream>>>(Zp, cbHi, cbLo, nullptr, S,
                                            32768, 448, 256);
    // VQ: indices (fp32), zq (bf16), per-row loss partials
    vq_kernel<<<8192, 256, 0, stream>>>(Zp, S, esq, G01, G02, G12, e0, e1, e2,
                                        Zq, out + 46137344, part);
    // z_q_out = zq @ W_out + b_out  (bf16 MFMA, fp32 out; threshold is loose)
    gemm_bt<<<dim3(256, 11), 256, 0, stream>>>(Zq, WoutT, b_out, out, 32768, 1408, 256);
    finalize_loss<<<1, 256, 0, stream>>>(part, out + 46235648);
}